// Round 3
// baseline (678.790 us; speedup 1.0000x reference)
//
#include <hip/hip_runtime.h>

#define N_TOK 65536
#define D 64
#define C_CODES 2048
#define DECAYF 0.8f
#define OMDF 0.2f
#define EPSF 1e-5f
#define NCHUNK 4
#define CHUNK (C_CODES / NCHUNK)

// output layout (floats), concatenated in reference return order
#define OUT_QUANT 0
#define OUT_IND   (N_TOK * D)               // 4194304
#define OUT_IND_  (OUT_IND)
#define OUT_EMB   (OUT_IND + N_TOK)         // 4259840
#define OUT_CS    (OUT_EMB + C_CODES * D)   // 4390912
#define OUT_EAVG  (OUT_CS + C_CODES)        // 4392960

__global__ void e2_kernel(const float* __restrict__ emb, float* __restrict__ e2) {
    int c = blockIdx.x * blockDim.x + threadIdx.x;
    const float4* er = (const float4*)(emb + (size_t)c * D);
    float s0 = 0.f, s1 = 0.f, s2 = 0.f, s3 = 0.f;
#pragma unroll
    for (int i = 0; i < D / 4; ++i) {
        float4 e = er[i];
        s0 = fmaf(e.x, e.x, s0);
        s1 = fmaf(e.y, e.y, s1);
        s2 = fmaf(e.z, e.z, s2);
        s3 = fmaf(e.w, e.w, s3);
    }
    e2[c] = (s0 + s1) + (s2 + s3);
}

// One thread = one token, one chunk of 512 codes. Arithmetic is BIT-IDENTICAL
// to the R1 version that validated (indices exact): 4-chain dot, dist2 =
// x2 + e2[c] - 2*dot, clip, u64 (dist_bits<<32 | c) min-reduce.
// __launch_bounds__(256,4) caps VGPR at 128 so the 16xfloat4 x-row stays
// resident (R1 compiled at VGPR=40 and re-fetched x per code -> 62% VALUBusy).
__global__ __launch_bounds__(256, 4) void dist_kernel(
        const float* __restrict__ x, const float* __restrict__ emb,
        const float* __restrict__ e2, unsigned long long* __restrict__ keys) {
    int token = blockIdx.x * blockDim.x + threadIdx.x;
    int chunk = blockIdx.y;
    const float4* xr = (const float4*)(x + (size_t)token * D);
    float4 xv[D / 4];
#pragma unroll
    for (int i = 0; i < D / 4; ++i) xv[i] = xr[i];
    float s0 = 0.f, s1 = 0.f, s2 = 0.f, s3 = 0.f;
#pragma unroll
    for (int i = 0; i < D / 4; ++i) {
        s0 = fmaf(xv[i].x, xv[i].x, s0);
        s1 = fmaf(xv[i].y, xv[i].y, s1);
        s2 = fmaf(xv[i].z, xv[i].z, s2);
        s3 = fmaf(xv[i].w, xv[i].w, s3);
    }
    float x2 = (s0 + s1) + (s2 + s3);

    unsigned long long best = ~0ull;
    int c0 = chunk * CHUNK;
    for (int c = c0; c < c0 + CHUNK; ++c) {
        const float4* er = (const float4*)(emb + (size_t)c * D);
        float d0 = 0.f, d1 = 0.f, d2 = 0.f, d3 = 0.f;
#pragma unroll
        for (int i = 0; i < D / 4; ++i) {
            float4 e = er[i];
            d0 = fmaf(xv[i].x, e.x, d0);
            d1 = fmaf(xv[i].y, e.y, d1);
            d2 = fmaf(xv[i].z, e.z, d2);
            d3 = fmaf(xv[i].w, e.w, d3);
        }
        float dot = (d0 + d1) + (d2 + d3);
        float dist2 = x2 + e2[c] - 2.0f * dot;
        dist2 = fmaxf(dist2, 0.0f);
        unsigned long long key =
            ((unsigned long long)__float_as_uint(dist2) << 32) | (unsigned int)c;
        best = key < best ? key : best;
    }
    keys[(size_t)chunk * N_TOK + token] = best;
}

__global__ void finalize_kernel(const unsigned long long* __restrict__ keys,
                                int* __restrict__ idx, float* __restrict__ out,
                                float* __restrict__ counts) {
    __shared__ float lcount[C_CODES];
    for (int i = threadIdx.x; i < C_CODES; i += blockDim.x) lcount[i] = 0.0f;
    __syncthreads();
    int n = blockIdx.x * blockDim.x + threadIdx.x;
    unsigned long long best = keys[n];
#pragma unroll
    for (int j = 1; j < NCHUNK; ++j) {
        unsigned long long k = keys[(size_t)j * N_TOK + n];
        best = k < best ? k : best;
    }
    int c = (int)(best & 0xffffffffull);
    idx[n] = c;
    out[OUT_IND + n] = (float)c;
    atomicAdd(&lcount[c], 1.0f);
    __syncthreads();
    for (int i = threadIdx.x; i < C_CODES; i += blockDim.x) {
        float v = lcount[i];
        if (v != 0.0f) atomicAdd(&counts[i], v);
    }
}

// quantize gather: 16 threads per token, one float4 each. Pure, no atomics.
__global__ void gather_kernel(const float* __restrict__ emb,
                              const int* __restrict__ idx,
                              float* __restrict__ out) {
    int g = blockIdx.x * blockDim.x + threadIdx.x;  // [0, N_TOK*16)
    int n = g >> 4;
    int j = g & 15;
    int c = idx[n];
    float4 e = ((const float4*)emb)[c * (D / 4) + j];
    ((float4*)(out + OUT_QUANT))[g] = e;
}

// Single block: EMA cluster-size + laplace smoothing + exclusive prefix sum
// of counts -> offsets/cursor for the counting sort.
__global__ void prefix_ema_kernel(const float* __restrict__ counts,
                                  const float* __restrict__ cluster_size,
                                  float* __restrict__ out,
                                  float* __restrict__ smoothed,
                                  int* __restrict__ offsets,
                                  int* __restrict__ cursor) {
    __shared__ float scan[256];
    __shared__ float red[256];
    int t = threadIdx.x;
    int base = t * 8;
    float cnt[8], ncs[8];
    float csum = 0.f, nsum = 0.f;
#pragma unroll
    for (int j = 0; j < 8; ++j) {
        cnt[j] = counts[base + j];
        csum += cnt[j];
        ncs[j] = cluster_size[base + j] * DECAYF + cnt[j] * OMDF;
        nsum += ncs[j];
        out[OUT_CS + base + j] = ncs[j];
    }
    scan[t] = csum;
    red[t] = nsum;
    __syncthreads();
    for (int s = 1; s < 256; s <<= 1) {
        float v = scan[t];
        float w = (t >= s) ? scan[t - s] : 0.f;
        __syncthreads();
        scan[t] = v + w;
        __syncthreads();
    }
    for (int s = 128; s > 0; s >>= 1) {
        if (t < s) red[t] += red[t + s];
        __syncthreads();
    }
    float tot = red[0];
    float run = (t == 0) ? 0.f : scan[t - 1];
#pragma unroll
    for (int j = 0; j < 8; ++j) {
        int o = (int)run;  // counts are small ints in float: exact
        offsets[base + j] = o;
        cursor[base + j] = o;
        run += cnt[j];
        smoothed[base + j] = (ncs[j] + EPSF) / (tot + (float)C_CODES * EPSF) * tot;
    }
}

// counting-sort position scatter: 65k int atomics over 2048 counters.
__global__ void scatter_pos_kernel(const int* __restrict__ idx,
                                   int* __restrict__ cursor,
                                   int* __restrict__ sorted) {
    int n = blockIdx.x * blockDim.x + threadIdx.x;
    int c = idx[n];
    int pos = atomicAdd(&cursor[c], 1);
    sorted[pos] = n;
}

// One wave per code: sum member token rows (no atomics), fuse embed_avg EMA
// and the renormalized new embedding. embed_sum never materializes.
__global__ void code_sum_kernel(const float* __restrict__ x,
                                const int* __restrict__ sorted,
                                const int* __restrict__ offsets,
                                const int* __restrict__ cursor,
                                const float* __restrict__ embed_avg,
                                const float* __restrict__ smoothed,
                                float* __restrict__ out) {
    int c = blockIdx.x;
    int lane = threadIdx.x;  // 64 = D
    int s0 = offsets[c];
    int s1 = cursor[c];  // == end after scatter_pos
    float sum = 0.f;
    for (int i = s0; i < s1; ++i) {
        int n = sorted[i];
        sum += x[(size_t)n * D + lane];
    }
    float na = embed_avg[(size_t)c * D + lane] * DECAYF + sum * OMDF;
    out[OUT_EAVG + (size_t)c * D + lane] = na;
    out[OUT_EMB + (size_t)c * D + lane] = na / smoothed[c];
}

extern "C" void kernel_launch(void* const* d_in, const int* in_sizes, int n_in,
                              void* d_out, int out_size, void* d_ws, size_t ws_size,
                              hipStream_t stream) {
    const float* x            = (const float*)d_in[0];  // (16,4096,64)
    const float* emb          = (const float*)d_in[1];  // (1,2048,64)
    const float* cluster_size = (const float*)d_in[2];  // (1,2048)
    const float* embed_avg    = (const float*)d_in[3];  // (1,2048,64)
    float* out = (float*)d_out;

    // workspace layout (keys first for 8B alignment)
    unsigned long long* keys = (unsigned long long*)d_ws;       // 4*65536 u64 = 2 MB
    float* e2       = (float*)(keys + (size_t)NCHUNK * N_TOK);  // 2048
    float* counts   = e2 + C_CODES;                             // 2048 (zeroed)
    float* smoothed = counts + C_CODES;                         // 2048
    int* offsets    = (int*)(smoothed + C_CODES);               // 2048
    int* cursor     = offsets + C_CODES;                        // 2048
    int* idx        = cursor + C_CODES;                         // 65536
    int* sorted     = idx + N_TOK;                              // 65536

    hipMemsetAsync(counts, 0, C_CODES * sizeof(float), stream);

    e2_kernel<<<C_CODES / 256, 256, 0, stream>>>(emb, e2);
    dist_kernel<<<dim3(N_TOK / 256, NCHUNK), 256, 0, stream>>>(x, emb, e2, keys);
    finalize_kernel<<<N_TOK / 256, 256, 0, stream>>>(keys, idx, out, counts);
    gather_kernel<<<(N_TOK * 16) / 256, 256, 0, stream>>>(emb, idx, out);
    prefix_ema_kernel<<<1, 256, 0, stream>>>(counts, cluster_size, out, smoothed,
                                             offsets, cursor);
    scatter_pos_kernel<<<N_TOK / 256, 256, 0, stream>>>(idx, cursor, sorted);
    code_sum_kernel<<<C_CODES, D, 0, stream>>>(x, sorted, offsets, cursor,
                                               embed_avg, smoothed, out);
}

// Round 4
// 334.049 us; speedup vs baseline: 2.0320x; 2.0320x over previous
//
#include <hip/hip_runtime.h>

#define N_TOK 65536
#define D 64
#define C_CODES 2048
#define DECAYF 0.8f
#define OMDF 0.2f
#define EPSF 1e-5f
#define NCHUNK 4
#define CHUNK (C_CODES / NCHUNK)
#define SEG 16  // sorted positions per wave in seg_sum

// output layout (floats), concatenated in reference return order
#define OUT_QUANT 0
#define OUT_IND   (N_TOK * D)               // 4194304
#define OUT_EMB   (OUT_IND + N_TOK)         // 4259840
#define OUT_CS    (OUT_EMB + C_CODES * D)   // 4390912
#define OUT_EAVG  (OUT_CS + C_CODES)        // 4392960

__global__ void e2_kernel(const float* __restrict__ emb, float* __restrict__ e2) {
    int c = blockIdx.x * blockDim.x + threadIdx.x;
    const float4* er = (const float4*)(emb + (size_t)c * D);
    float s0 = 0.f, s1 = 0.f, s2 = 0.f, s3 = 0.f;
#pragma unroll
    for (int i = 0; i < D / 4; ++i) {
        float4 e = er[i];
        s0 = fmaf(e.x, e.x, s0);
        s1 = fmaf(e.y, e.y, s1);
        s2 = fmaf(e.z, e.z, s2);
        s3 = fmaf(e.w, e.w, s3);
    }
    e2[c] = (s0 + s1) + (s2 + s3);
}

// BIT-IDENTICAL arithmetic to the validated R1/R3 version. Do not touch the
// expression tree: argmin ties are resolved by exact fp bit patterns.
__global__ __launch_bounds__(256, 4) void dist_kernel(
        const float* __restrict__ x, const float* __restrict__ emb,
        const float* __restrict__ e2, unsigned long long* __restrict__ keys) {
    int token = blockIdx.x * blockDim.x + threadIdx.x;
    int chunk = blockIdx.y;
    const float4* xr = (const float4*)(x + (size_t)token * D);
    float4 xv[D / 4];
#pragma unroll
    for (int i = 0; i < D / 4; ++i) xv[i] = xr[i];
    float s0 = 0.f, s1 = 0.f, s2 = 0.f, s3 = 0.f;
#pragma unroll
    for (int i = 0; i < D / 4; ++i) {
        s0 = fmaf(xv[i].x, xv[i].x, s0);
        s1 = fmaf(xv[i].y, xv[i].y, s1);
        s2 = fmaf(xv[i].z, xv[i].z, s2);
        s3 = fmaf(xv[i].w, xv[i].w, s3);
    }
    float x2 = (s0 + s1) + (s2 + s3);

    unsigned long long best = ~0ull;
    int c0 = chunk * CHUNK;
    for (int c = c0; c < c0 + CHUNK; ++c) {
        const float4* er = (const float4*)(emb + (size_t)c * D);
        float d0 = 0.f, d1 = 0.f, d2 = 0.f, d3 = 0.f;
#pragma unroll
        for (int i = 0; i < D / 4; ++i) {
            float4 e = er[i];
            d0 = fmaf(xv[i].x, e.x, d0);
            d1 = fmaf(xv[i].y, e.y, d1);
            d2 = fmaf(xv[i].z, e.z, d2);
            d3 = fmaf(xv[i].w, e.w, d3);
        }
        float dot = (d0 + d1) + (d2 + d3);
        float dist2 = x2 + e2[c] - 2.0f * dot;
        dist2 = fmaxf(dist2, 0.0f);
        unsigned long long key =
            ((unsigned long long)__float_as_uint(dist2) << 32) | (unsigned int)c;
        best = key < best ? key : best;
    }
    keys[(size_t)chunk * N_TOK + token] = best;
}

__global__ void finalize_kernel(const unsigned long long* __restrict__ keys,
                                int* __restrict__ idx, float* __restrict__ out,
                                float* __restrict__ counts) {
    __shared__ float lcount[C_CODES];
    for (int i = threadIdx.x; i < C_CODES; i += blockDim.x) lcount[i] = 0.0f;
    __syncthreads();
    int n = blockIdx.x * blockDim.x + threadIdx.x;
    unsigned long long best = keys[n];
#pragma unroll
    for (int j = 1; j < NCHUNK; ++j) {
        unsigned long long k = keys[(size_t)j * N_TOK + n];
        best = k < best ? k : best;
    }
    int c = (int)(best & 0xffffffffull);
    idx[n] = c;
    out[OUT_IND + n] = (float)c;
    atomicAdd(&lcount[c], 1.0f);
    __syncthreads();
    for (int i = threadIdx.x; i < C_CODES; i += blockDim.x) {
        float v = lcount[i];
        if (v != 0.0f) atomicAdd(&counts[i], v);
    }
}

// quantize gather: 16 threads per token, one float4 each.
__global__ void gather_kernel(const float* __restrict__ emb,
                              const int* __restrict__ idx,
                              float* __restrict__ out) {
    int g = blockIdx.x * blockDim.x + threadIdx.x;  // [0, N_TOK*16)
    int n = g >> 4;
    int j = g & 15;
    int c = idx[n];
    float4 e = ((const float4*)emb)[c * (D / 4) + j];
    ((float4*)(out + OUT_QUANT))[g] = e;
}

// Single block: EMA cluster-size + laplace smoothing + exclusive prefix sum.
__global__ void prefix_ema_kernel(const float* __restrict__ counts,
                                  const float* __restrict__ cluster_size,
                                  float* __restrict__ out,
                                  float* __restrict__ smoothed,
                                  int* __restrict__ cursor) {
    __shared__ float scan[256];
    __shared__ float red[256];
    int t = threadIdx.x;
    int base = t * 8;
    float cnt[8], ncs[8];
    float csum = 0.f, nsum = 0.f;
#pragma unroll
    for (int j = 0; j < 8; ++j) {
        cnt[j] = counts[base + j];
        csum += cnt[j];
        ncs[j] = cluster_size[base + j] * DECAYF + cnt[j] * OMDF;
        nsum += ncs[j];
        out[OUT_CS + base + j] = ncs[j];
    }
    scan[t] = csum;
    red[t] = nsum;
    __syncthreads();
    for (int s = 1; s < 256; s <<= 1) {
        float v = scan[t];
        float w = (t >= s) ? scan[t - s] : 0.f;
        __syncthreads();
        scan[t] = v + w;
        __syncthreads();
    }
    for (int s = 128; s > 0; s >>= 1) {
        if (t < s) red[t] += red[t + s];
        __syncthreads();
    }
    float tot = red[0];
    float run = (t == 0) ? 0.f : scan[t - 1];
#pragma unroll
    for (int j = 0; j < 8; ++j) {
        cursor[base + j] = (int)run;  // counts are small ints in float: exact
        run += cnt[j];
        smoothed[base + j] = (ncs[j] + EPSF) / (tot + (float)C_CODES * EPSF) * tot;
    }
}

// counting-sort position scatter; entry packs (code<<16 | token) so the
// segmented-sum pass needs only ONE load per position.
__global__ void scatter_pos_kernel(const int* __restrict__ idx,
                                   int* __restrict__ cursor,
                                   unsigned int* __restrict__ sorted) {
    int n = blockIdx.x * blockDim.x + threadIdx.x;
    int c = idx[n];
    int pos = atomicAdd(&cursor[c], 1);
    sorted[pos] = ((unsigned int)c << 16) | (unsigned int)n;
}

// Segmented sum over sorted positions: each wave owns SEG contiguous entries
// (skew-immune), loads all SEG x-rows with independent in-flight loads, and
// flushes one 64-lane atomicAdd per code-run boundary (~0.4M atomics total).
__global__ __launch_bounds__(256) void seg_sum_kernel(
        const float* __restrict__ x, const unsigned int* __restrict__ sorted,
        float* __restrict__ embed_sum) {
    int lane = threadIdx.x & 63;
    int q = blockIdx.x * 4 + (threadIdx.x >> 6);  // wave id
    int p0 = q * SEG;

    unsigned int mine = (lane < SEG) ? sorted[p0 + lane] : 0u;
    unsigned int pk[SEG];
#pragma unroll
    for (int j = 0; j < SEG; ++j) pk[j] = __shfl(mine, j, 64);

    float xv[SEG];
#pragma unroll
    for (int j = 0; j < SEG; ++j)
        xv[j] = x[(size_t)(pk[j] & 0xffffu) * D + lane];  // 16 independent loads

    unsigned int run_c = 0xffffffffu;
    float sum = 0.f;
#pragma unroll
    for (int j = 0; j < SEG; ++j) {
        unsigned int c = pk[j] >> 16;  // wave-uniform
        if (c != run_c) {
            if (run_c != 0xffffffffu)
                atomicAdd(&embed_sum[(size_t)run_c * D + lane], sum);
            run_c = c;
            sum = 0.f;
        }
        sum += xv[j];
    }
    atomicAdd(&embed_sum[(size_t)run_c * D + lane], sum);
}

__global__ void ema_embed_kernel(const float* __restrict__ embed_avg,
                                 const float* __restrict__ embed_sum,
                                 const float* __restrict__ smoothed,
                                 float* __restrict__ out) {
    int g = blockIdx.x * blockDim.x + threadIdx.x;  // [0, C_CODES*16)
    int c = g >> 4;
    float4 ea = ((const float4*)embed_avg)[g];
    float4 es = ((const float4*)embed_sum)[g];
    float4 na;
    na.x = ea.x * DECAYF + es.x * OMDF;
    na.y = ea.y * DECAYF + es.y * OMDF;
    na.z = ea.z * DECAYF + es.z * OMDF;
    na.w = ea.w * DECAYF + es.w * OMDF;
    ((float4*)(out + OUT_EAVG))[g] = na;
    float sm = smoothed[c];
    float4 ne;
    ne.x = na.x / sm;
    ne.y = na.y / sm;
    ne.z = na.z / sm;
    ne.w = na.w / sm;
    ((float4*)(out + OUT_EMB))[g] = ne;
}

extern "C" void kernel_launch(void* const* d_in, const int* in_sizes, int n_in,
                              void* d_out, int out_size, void* d_ws, size_t ws_size,
                              hipStream_t stream) {
    const float* x            = (const float*)d_in[0];  // (16,4096,64)
    const float* emb          = (const float*)d_in[1];  // (1,2048,64)
    const float* cluster_size = (const float*)d_in[2];  // (1,2048)
    const float* embed_avg    = (const float*)d_in[3];  // (1,2048,64)
    float* out = (float*)d_out;

    // workspace layout (keys first for 8B alignment)
    unsigned long long* keys = (unsigned long long*)d_ws;       // 4*65536 u64 = 2 MB
    float* e2        = (float*)(keys + (size_t)NCHUNK * N_TOK); // 2048
    float* counts    = e2 + C_CODES;                            // 2048 (zeroed)
    float* smoothed  = counts + C_CODES;                        // 2048
    int* cursor      = (int*)(smoothed + C_CODES);              // 2048
    int* idx         = cursor + C_CODES;                        // 65536
    unsigned int* sorted = (unsigned int*)(idx + N_TOK);        // 65536
    float* embed_sum = (float*)(sorted + N_TOK);                // 131072 (zeroed)

    hipMemsetAsync(counts, 0, C_CODES * sizeof(float), stream);
    hipMemsetAsync(embed_sum, 0, (size_t)C_CODES * D * sizeof(float), stream);

    e2_kernel<<<C_CODES / 256, 256, 0, stream>>>(emb, e2);
    dist_kernel<<<dim3(N_TOK / 256, NCHUNK), 256, 0, stream>>>(x, emb, e2, keys);
    finalize_kernel<<<N_TOK / 256, 256, 0, stream>>>(keys, idx, out, counts);
    gather_kernel<<<(N_TOK * 16) / 256, 256, 0, stream>>>(emb, idx, out);
    prefix_ema_kernel<<<1, 256, 0, stream>>>(counts, cluster_size, out, smoothed, cursor);
    scatter_pos_kernel<<<N_TOK / 256, 256, 0, stream>>>(idx, cursor, sorted);
    seg_sum_kernel<<<(N_TOK / SEG) / 4, 256, 0, stream>>>(x, sorted, embed_sum);
    ema_embed_kernel<<<(C_CODES * 16) / 256, 256, 0, stream>>>(embed_avg, embed_sum,
                                                              smoothed, out);
}